// Round 13
// baseline (156.547 us; speedup 1.0000x reference)
//
#include <hip/hip_runtime.h>
#include <cstdint>
#include <cstddef>

// ---------------------------------------------------------------------------
// x = mean_i( softmax(q_i K^T / 16) ) @ h   with q = h@Wq, k = h@Wk
//   = sum_j c_j h_j,  c_j = (1/N) sum_i exp(e_ij)/l_i,  l_i = sum_j exp(e_ij)
//
// Round 13: single variable vs R12 — qk_pass uses 4 accumulators (2 tiles x
// 2 rowtiles) and ONE exp epilogue per barrier group instead of per tile.
// 64-MFMA uninterrupted burst per group per wave (2067 SIMD-cyc), then one
// batched 64-exp epilogue (~350 cyc): halves epilogue frequency and lets the
// two co-resident waves cover each other's VALU bursts. Reg cost +32 (~250
// total, under launch_bounds(512,2)'s 256 cap — spill is the tracked risk).
// proj / finish / launcher byte-identical to R12 (controls).
//
// Accounting model (R12 profile): total 147.4 = harness d_ws fill ~44 (fixed
// tax, 268 MB poison) + proj ~10 + qk 2x~40 + finish ~2.5 + ~12 graph gaps.
//
// ws: [0,4MB) q bf16 frag-major | [4MB,8MB) k frag-major | l fp32[8192] |
//     c fp32[8192]
// Frag-major (32x32 MFMA A/B layout) per 32-row tile = 16 KB:
//   elem (i,d): tile i>>5, slot (d>>4)*64 + (i&31) + 32*((d>>3)&1), byte d&7;
//   dword index within tile = a0*64 + lane (lane-linear 16B).
// ---------------------------------------------------------------------------

#define N_ROWS 8192
#define DIM    256

typedef __bf16 bf16x8 __attribute__((ext_vector_type(8)));
typedef unsigned short u16x8 __attribute__((ext_vector_type(8)));
typedef float f32x16 __attribute__((ext_vector_type(16)));

__device__ __forceinline__ uint16_t f2bf(float f) {
    uint32_t u = __float_as_uint(f);
    uint32_t r = (u + 0x7fffu + ((u >> 16) & 1u)) >> 16;   // RTN-even
    return (uint16_t)r;
}

__device__ __forceinline__ float fexp2(float x) {
#if __has_builtin(__builtin_amdgcn_exp2f)
    return __builtin_amdgcn_exp2f(x);                      // v_exp_f32 = 2^x
#else
    return __expf(x * 0.69314718056f);
#endif
}

// async global->LDS, 16B/lane; lds dst is wave-uniform base + lane*16
__device__ __forceinline__ void gld16(const void* gsrc, void* ldst) {
    __builtin_amdgcn_global_load_lds(
        (const __attribute__((address_space(1))) unsigned int*)gsrc,
        (__attribute__((address_space(3))) unsigned int*)ldst, 16, 0, 0);
}

// ---------------------------------------------------------------------------
// Kernel 1 (R11/R12 verbatim): proj. Grid 1024: bid = rt*4 + ph. h staged
// coalesced to LDS (stride-260), W per-lane scalar loads, proven repack.
// Zero-inits l_arr / c_arr / out.
// ---------------------------------------------------------------------------
__global__ __launch_bounds__(256) void proj_kernel(
        const float* __restrict__ h, const float* __restrict__ Wq,
        const float* __restrict__ Wk, uint16_t* __restrict__ qf,
        uint16_t* __restrict__ kf, float* __restrict__ l_arr,
        float* __restrict__ c_arr, float* __restrict__ out) {
    __shared__ alignas(16) float hbf[32 * 260];       // 33.3 KB h stage
    __shared__ alignas(16) uint16_t rep[4][1024];     // 8 KB wave-private repack
    const int tid = threadIdx.x, lane = tid & 63, wave = tid >> 6;
    const int bid = blockIdx.x;
    const int rt = bid >> 2, ph = bid & 3;
    const int which = ph >> 1, p = ph & 1;

    if (bid < 32)       l_arr[bid * 256 + tid] = 0.0f;
    else if (bid < 64)  c_arr[(bid - 32) * 256 + tid] = 0.0f;
    else if (bid == 64) out[tid] = 0.0f;

    const float* __restrict__ W = which ? Wk : Wq;
    uint16_t* __restrict__ dst = which ? kf : qf;
    const float scale = which ? 1.0f : (0.0625f * 1.44269504089f);

    for (int i = tid; i < 2048; i += 256) {
        int r = i >> 6, c = (i & 63) * 4;
        *(float4*)&hbf[r * 260 + c] = *(const float4*)&h[(size_t)(rt * 32 + r) * DIM + c];
    }
    __syncthreads();

    bf16x8 afrag[16];
    {
        const int r = lane & 31;
#pragma unroll
        for (int a0 = 0; a0 < 16; a0++) {
            const int c0 = a0 * 16 + (lane >> 5) * 8;
            float4 f0 = *(const float4*)&hbf[r * 260 + c0];
            float4 f1 = *(const float4*)&hbf[r * 260 + c0 + 4];
            u16x8 f;
            f[0] = f2bf(f0.x); f[1] = f2bf(f0.y); f[2] = f2bf(f0.z); f[3] = f2bf(f0.w);
            f[4] = f2bf(f1.x); f[5] = f2bf(f1.y); f[6] = f2bf(f1.z); f[7] = f2bf(f1.w);
            afrag[a0] = __builtin_bit_cast(bf16x8, f);
        }
    }

    const int ctl = wave;
    const int cl = ctl * 32 + (lane & 31);
    f32x16 acc;
#pragma unroll
    for (int i = 0; i < 16; i++) acc[i] = 0.0f;
#pragma unroll
    for (int a0 = 0; a0 < 16; a0++) {
        const int kb = a0 * 16 + (lane >> 5) * 8;
        u16x8 f;
#pragma unroll
        for (int j = 0; j < 8; j++)
            f[j] = f2bf(W[(size_t)(kb + j) * DIM + p * 128 + cl]);
        acc = __builtin_amdgcn_mfma_f32_32x32x16_bf16(
            afrag[a0], __builtin_bit_cast(bf16x8, f), acc, 0, 0, 0);
    }

    {
        const int dcl = lane & 31;
        const int a0o = dcl >> 4, hi = (dcl >> 3) & 1, jj = dcl & 7;
        const int ilb = 4 * (lane >> 5);
#pragma unroll
        for (int reg = 0; reg < 16; reg++) {
            int il = ilb + (reg & 3) + 8 * (reg >> 2);
            rep[wave][(size_t)((a0o * 64) + il + 32 * hi) * 8 + jj] =
                f2bf(acc[reg] * scale);
        }
        const uint4* rv = (const uint4*)&rep[wave][0];  // wave-local RAW
        uint4* gp = (uint4*)(dst + (size_t)rt * 8192 +
                             (size_t)(p * 4 + ctl) * 1024);
        gp[lane * 2]     = rv[lane * 2];
        gp[lane * 2 + 1] = rv[lane * 2 + 1];
    }
}

// ---------------------------------------------------------------------------
// Kernels 2/3: two QK^T passes, 512-thread blocks, 4-acc group batching.
// Grid 256 = 16 rowblocks(512 rows) x 16 colchunks(512 cols), 1 block/CU.
// Per barrier group: 32 KB (2 k-tiles) staged async, double-buffered;
// 64-MFMA burst (2 tiles x 2 rowtiles, 4 acc chains), ONE epilogue/group.
// MODE 0: l_i row sums. MODE 1: c_j weighted col sums.
// ---------------------------------------------------------------------------
template <int MODE>
__global__ __launch_bounds__(512, 2) void qk_pass(
        const uint16_t* __restrict__ qf, const uint16_t* __restrict__ kf,
        float* __restrict__ l_arr, float* __restrict__ c_arr) {
    __shared__ alignas(16) uint16_t ktile[2][16384];  // 2 x 32 KB (2 tiles each)
    __shared__ float c_lds[512];
    const int tid = threadIdx.x, lane = tid & 63, wave = tid >> 6;  // wave 0..7
    const int bid = blockIdx.x;
    const int cc = bid & 15, rb = bid >> 4;           // rb 0..15
    const int t0 = rb * 16 + wave * 2;                // wave's rowtiles t0, t0+1
    const int row0 = t0 * 32;

    // resident q: 2 rowtiles x 16 K-chunks = 128 regs
    const uint4* qp = (const uint4*)qf;
    bf16x8 q0[16], q1[16];
#pragma unroll
    for (int a0 = 0; a0 < 16; a0++) {
        q0[a0] = __builtin_bit_cast(bf16x8, qp[(size_t)t0 * 1024 + a0 * 64 + lane]);
        q1[a0] = __builtin_bit_cast(bf16x8, qp[(size_t)(t0 + 1) * 1024 + a0 * 64 + lane]);
    }

    float rs0[16], rs1[16];   // MODE 0 partials
    float rr0[16], rr1[16];   // MODE 1: 1/(N*l_i)
    if (MODE == 0) {
#pragma unroll
        for (int r = 0; r < 16; r++) { rs0[r] = 0.0f; rs1[r] = 0.0f; }
    } else {
#pragma unroll
        for (int r = 0; r < 16; r++) {
            int ro = (r & 3) + 8 * (r >> 2) + 4 * (lane >> 5);
            rr0[r] = 1.0f / (8192.0f * l_arr[row0 + ro]);
            rr1[r] = 1.0f / (8192.0f * l_arr[row0 + 32 + ro]);
        }
        if (tid < 512) c_lds[tid] = 0.0f;
    }

    const char* ksrc = (const char*)kf + (size_t)cc * 16 * 16384;  // 16 tiles

    {   // prologue: stage tiles 0,1 (32 KB) -> buffer 0; each wave 4 KB
        const char* s0 = ksrc + wave * 4096 + lane * 16;
        char* d0 = (char*)&ktile[0][0] + wave * 4096;
#pragma unroll
        for (int it = 0; it < 4; it++) gld16(s0 + it * 1024, d0 + it * 1024);
    }

    for (int g = 0; g < 8; g++) {
        __syncthreads();          // vmcnt drained: group g staged; other
                                  // buffer's readers all done
        if (g < 7) {              // prefetch group g+1 (tiles 2g+2, 2g+3)
            const char* sn = ksrc + (size_t)(2 * g + 2) * 16384 + wave * 4096 + lane * 16;
            char* dn = (char*)&ktile[(g + 1) & 1][0] + wave * 4096;
#pragma unroll
            for (int it = 0; it < 4; it++) gld16(sn + it * 1024, dn + it * 1024);
        }

        // 64-MFMA burst: 2 tiles x (2 rowtiles x 16 K-chunks), 4 acc chains
        f32x16 a00, a01, a10, a11;
#pragma unroll
        for (int i = 0; i < 16; i++) { a00[i] = 0.0f; a01[i] = 0.0f;
                                       a10[i] = 0.0f; a11[i] = 0.0f; }
        {
            const uint16_t* kt0 = &ktile[g & 1][0];
            const uint16_t* kt1 = &ktile[g & 1][8192];
#pragma unroll
            for (int a0 = 0; a0 < 16; a0++) {
                bf16x8 b0 = __builtin_bit_cast(bf16x8,
                    *(const u16x8*)&kt0[(size_t)(a0 * 64 + lane) * 8]);
                a00 = __builtin_amdgcn_mfma_f32_32x32x16_bf16(q0[a0], b0, a00, 0, 0, 0);
                a01 = __builtin_amdgcn_mfma_f32_32x32x16_bf16(q1[a0], b0, a01, 0, 0, 0);
            }
#pragma unroll
            for (int a0 = 0; a0 < 16; a0++) {
                bf16x8 b1 = __builtin_bit_cast(bf16x8,
                    *(const u16x8*)&kt1[(size_t)(a0 * 64 + lane) * 8]);
                a10 = __builtin_amdgcn_mfma_f32_32x32x16_bf16(q0[a0], b1, a10, 0, 0, 0);
                a11 = __builtin_amdgcn_mfma_f32_32x32x16_bf16(q1[a0], b1, a11, 0, 0, 0);
            }
        }

        // ONE epilogue per group (64 exp), off the per-tile critical path
        if (MODE == 0) {
#pragma unroll
            for (int r = 0; r < 16; r++) {
                rs0[r] += fexp2(a00[r]) + fexp2(a10[r]);
                rs1[r] += fexp2(a01[r]) + fexp2(a11[r]);
            }
        } else {
            float s0 = 0.0f, s1 = 0.0f;
#pragma unroll
            for (int r = 0; r < 16; r++) {
                s0 += fexp2(a00[r]) * rr0[r];
                s0 += fexp2(a01[r]) * rr1[r];
                s1 += fexp2(a10[r]) * rr0[r];
                s1 += fexp2(a11[r]) * rr1[r];
            }
            s0 += __shfl_xor(s0, 32);                 // fold row halves per col
            s1 += __shfl_xor(s1, 32);
            if (lane < 32) {
                atomicAdd(&c_lds[(2 * g) * 32 + lane], s0);
                atomicAdd(&c_lds[(2 * g + 1) * 32 + lane], s1);
            }
        }
    }

    if (MODE == 0) {
#pragma unroll
        for (int r = 0; r < 16; r++) {
            float v0 = rs0[r], v1 = rs1[r];
            v0 += __shfl_xor(v0, 1);  v0 += __shfl_xor(v0, 2);
            v0 += __shfl_xor(v0, 4);  v0 += __shfl_xor(v0, 8);
            v0 += __shfl_xor(v0, 16);
            v1 += __shfl_xor(v1, 1);  v1 += __shfl_xor(v1, 2);
            v1 += __shfl_xor(v1, 4);  v1 += __shfl_xor(v1, 8);
            v1 += __shfl_xor(v1, 16);
            if ((lane & 31) == 0) {
                int ro = (r & 3) + 8 * (r >> 2) + 4 * (lane >> 5);
                atomicAdd(&l_arr[row0 + ro], v0);
                atomicAdd(&l_arr[row0 + 32 + ro], v1);
            }
        }
    } else {
        __syncthreads();
        if (tid < 512) atomicAdd(&c_arr[cc * 512 + tid], c_lds[tid]);
    }
}

// ---------------------------------------------------------------------------
// Kernel 4 (R8 verbatim): x = c @ h. 256 blocks x 32 rows, fully unrolled.
// ---------------------------------------------------------------------------
__global__ __launch_bounds__(256) void finish_kernel(
        const float* __restrict__ h, const float* __restrict__ c_arr,
        float* __restrict__ out) {
    const int d = threadIdx.x;
    const int j0 = blockIdx.x * 32;
    float acc = 0.0f;
#pragma unroll
    for (int jj = 0; jj < 32; jj++)
        acc += c_arr[j0 + jj] * h[(size_t)(j0 + jj) * DIM + d];
    atomicAdd(&out[d], acc);
}

// ---------------------------------------------------------------------------
extern "C" void kernel_launch(void* const* d_in, const int* in_sizes, int n_in,
                              void* d_out, int out_size, void* d_ws, size_t ws_size,
                              hipStream_t stream) {
    const float* h  = (const float*)d_in[0];
    const float* Wq = (const float*)d_in[1];
    const float* Wk = (const float*)d_in[2];

    uint16_t* qf = (uint16_t*)d_ws;
    uint16_t* kf = qf + (size_t)N_ROWS * DIM;                  // +4 MB
    float* l_arr = (float*)((char*)d_ws + (size_t)8 * 1024 * 1024);
    float* c_arr = l_arr + N_ROWS;
    float* out = (float*)d_out;

    proj_kernel<<<1024, 256, 0, stream>>>(h, Wq, Wk, qf, kf, l_arr, c_arr, out);
    qk_pass<0><<<256, 512, 0, stream>>>(qf, kf, l_arr, c_arr);
    qk_pass<1><<<256, 512, 0, stream>>>(qf, kf, l_arr, c_arr);
    finish_kernel<<<256, 256, 0, stream>>>(h, c_arr, out);
}